// Round 7
// baseline (119.100 us; speedup 1.0000x reference)
//
#include <hip/hip_runtime.h>
#include <hip/hip_bf16.h>

#define BATCH 4
#define CHAN 128
#define HGT 96
#define WID 160
#define HW (HGT * WID)
#define THREADS 512
#define TENSOR_ELEMS (BATCH * CHAN * HGT * WID)
#define WS_NEED ((size_t)(2 * (size_t)TENSOR_ELEMS * 2))   // src + tgt, NHWC bf16

typedef __attribute__((ext_vector_type(8))) short short8;
typedef __attribute__((ext_vector_type(4))) float float4v;

// Output channel index for displacement (dy,dx), matching _displacements(4) order.
__device__ __forceinline__ int chan_of(int dy, int dx) {
    if (dy == 0 && dx == 0) return 0;
    if (dx == 0) { int i = dy < 0 ? -dy : dy; return 1 + (i - 1) * 20 + (dy < 0 ? 0 : 1); }
    if (dy == 0) { int i = dx < 0 ? -dx : dx; return 1 + (i - 1) * 20 + (dx < 0 ? 2 : 3); }
    int i = dy < 0 ? -dy : dy;
    int j = dx < 0 ? -dx : dx;
    int s = (dy < 0) ? (dx < 0 ? 0 : 2) : (dx < 0 ? 3 : 1);
    return 1 + (i - 1) * 20 + 4 + (j - 1) * 4 + s;
}

// Packed fp32x2 -> bf16x2 (v_cvt_pk_bf16_f32).
__device__ __forceinline__ unsigned pk2(float a, float b) {
    __hip_bfloat162 h = __float22bfloat162_rn(make_float2(a, b));
    unsigned u;
    __builtin_memcpy(&u, &h, 4);
    return u;
}

union sl_u { uint4 v; short8 s; };

// ---------------------------------------------------------------------------
// Pre-pass: NCHW f32 -> NHWC bf16 for BOTH tensors (R2-verified structure).
// Coalesced f32 reads, LDS transpose, fully coalesced 16B writes. BW-bound.
// ---------------------------------------------------------------------------
__global__ __launch_bounds__(256)
void nhwc_bf16_kernel(const float* __restrict__ src,
                      const float* __restrict__ tgt,
                      ushort* __restrict__ ws) {
    __shared__ unsigned s_t[64][65];
    int r = blockIdx.x;                 // 3 * 96 * 4 * 2 = 2304
    const int xb = r % 3; r /= 3;
    const int y  = r % HGT; r /= HGT;
    const int b  = r % BATCH; r /= BATCH;
    const float* in = r ? tgt : src;
    ushort* op0 = ws + (size_t)r * TENSOR_ELEMS;
    const int x0 = xb * 64;
    const int npx = (x0 + 64 <= WID) ? 64 : (WID - x0);   // 64 or 32

    const int t  = threadIdx.x;
    const int x1 = t & 63, cp0 = t >> 6;
    if (x1 < npx) {
        const int base = (b * CHAN * HGT + y) * WID + x0 + x1;  // channel 0
        #pragma unroll
        for (int i = 0; i < 16; ++i) {
            const int cp = cp0 + i * 4;                 // channel pair 0..63
            s_t[cp][x1] = pk2(in[base + (2 * cp) * HW],
                              in[base + (2 * cp + 1) * HW]);
        }
    }
    __syncthreads();
    const int x2 = t >> 2, g = t & 3;
    if (x2 < npx) {
        ushort* op = op0 + ((size_t)(b * HGT + y) * WID + x0 + x2) * CHAN + g * 32;
        #pragma unroll
        for (int k = 0; k < 4; ++k) {
            uint4 v;
            v.x = s_t[g * 16 + k * 4 + 0][x2];
            v.y = s_t[g * 16 + k * 4 + 1][x2];
            v.z = s_t[g * 16 + k * 4 + 2][x2];
            v.w = s_t[g * 16 + k * 4 + 3][x2];
            *(uint4*)(op + k * 8) = v;
        }
    }
}

// ---------------------------------------------------------------------------
// Main kernel: block = (b, y-quad, x-tile), all 81 displacements, 512 threads
// (8 waves; waves 0-3 dy 0-3, waves 4-7 dy 4-8). All staging is DMA or
// single-exposure vector loads — NO register payloads (R1/R5 lesson:
// VGPR-payload staging is re-serialized by the compiler).
//   B: 9 global_load_lds/thread from NHWC bf16 (XOR-octet source swizzle,
//      linear LDS dest, one vmcnt drain at the barrier, 0 bank conflicts).
//   A: 4 short8 NHWC loads (16 lines/instr, one exposure, 16 VGPRs).
// Epilogue: verified LDS-transpose store path.
// ---------------------------------------------------------------------------
__global__ __launch_bounds__(THREADS, 4)
void cost_volume_mfma(const ushort* __restrict__ srcT,
                      const ushort* __restrict__ tgtT,
                      float* __restrict__ out) {
    // 12*24*16 = 4608 DMA slots + 128 pad (nt=1 band-masked reads at x<=31).
    __shared__ __align__(16) uint4 s_b[4736];   // 75776 B -> 2 blocks/CU
    __shared__ int s_tab[81];                   // cix -> oc*HW

    const int tid  = threadIdx.x;
    const int wv   = tid >> 6;        // 0..7
    const int wvy  = wv & 3;          // y sub-row
    const int wvd  = wv >> 2;         // 0: dy 0-3, 1: dy 4-8
    const int lane = tid & 63;
    const int q    = lane >> 4;
    const int ln   = lane & 15;

    // XCD-affinity swizzle: blockIdx%8 -> (batch, y-half) slab.
    const int w    = blockIdx.x;      // 0..959
    const int slab = w & 7;
    const int b    = slab >> 1;
    const int yh   = slab & 1;
    const int t    = w >> 3;          // 0..119
    const int x0   = (t % 10) * 16;
    const int y0   = yh * 48 + (t / 10) * 4;

    // Table build first: its lgkmcnt drain merges into the pre-compute barrier.
    if (tid < 81) s_tab[tid] = chan_of(tid / 9 - 4, tid % 9 - 4) * HW;

    // ---- stage B: 4608 slots, 9 DMA/thread; slot u=(row*24+x)*16+j holds
    // octet j^(x&15); read for octet o fetches slot o^(x&15).
    const ushort* tbase = tgtT + (size_t)b * HGT * WID * CHAN;
    #pragma unroll
    for (int k = 0; k < 9; ++k) {
        const int u   = k * THREADS + tid;
        const int j   = u & 15;
        const int v16 = u >> 4;              // row*24 + x, 0..287
        const int row = v16 / 24;
        const int x   = v16 - row * 24;
        const int gr  = y0 - 4 + row;        // rows y0-4 .. y0+7
        const int gx  = x0 - 4 + x;
        const int oct = j ^ (x & 15);
        unsigned* lp = (unsigned*)&s_b[k * THREADS + (tid & ~63)];  // wave base
        if (((unsigned)gr < (unsigned)HGT) && ((unsigned)gx < (unsigned)WID)) {
            const unsigned* gp =
                (const unsigned*)(tbase + ((gr * WID + gx) * CHAN + oct * 8));
            __builtin_amdgcn_global_load_lds(gp, lp, 16, 0, 0);
        } else {
            s_b[u] = make_uint4(0u, 0u, 0u, 0u);   // disjoint from DMA targets
        }
    }

    // ---- A fragments: 4 x 16B contiguous NHWC loads (one exposure) ----
    const int y = y0 + wvy;
    const ushort* abase =
        srcT + ((size_t)(b * HGT + y) * WID + x0 + ln) * CHAN + q * 8;
    short8 afr[4];
    #pragma unroll
    for (int ks = 0; ks < 4; ++ks)
        afr[ks] = *(const short8*)(abase + ks * 32);

    __syncthreads();   // drains DMA (vmcnt) + zero-fill + table (lgkmcnt)

    // ---- compute: this wave's 4 or 5 dys x (8 ds_read_b128 + 8 MFMA) ----
    float4v aa0[5], aa1[5];
    #define COMPUTE_DY(DD, DYI)                                               \
        {                                                                     \
            const int rr = wvy + (DYI);                                       \
            float4v a0 = (float4v){0.f, 0.f, 0.f, 0.f};                       \
            float4v a1 = (float4v){0.f, 0.f, 0.f, 0.f};                       \
            _Pragma("unroll")                                                 \
            for (int ks = 0; ks < 4; ++ks) {                                  \
                sl_u b0;   /* nt=0: x = ln */                                 \
                b0.v = s_b[(rr * 24 + ln) * 16 + ((q + ks * 4) ^ ln)];        \
                a0 = __builtin_amdgcn_mfma_f32_16x16x32_bf16(afr[ks], b0.s, a0, 0, 0, 0); \
            }                                                                 \
            _Pragma("unroll")                                                 \
            for (int ks = 0; ks < 4; ++ks) {                                  \
                sl_u b1;   /* nt=1: x = 16+ln */                              \
                b1.v = s_b[(rr * 24 + 16 + ln) * 16 + ((q + ks * 4) ^ ln)];   \
                a1 = __builtin_amdgcn_mfma_f32_16x16x32_bf16(afr[ks], b1.s, a1, 0, 0, 0); \
            }                                                                 \
            aa0[DD] = a0; aa1[DD] = a1;                                       \
        }
    if (wvd == 0) {
        #pragma unroll
        for (int dd = 0; dd < 4; ++dd) COMPUTE_DY(dd, dd)
    } else {
        #pragma unroll
        for (int dd = 0; dd < 5; ++dd) COMPUTE_DY(dd, dd + 4)
    }

    __syncthreads();   // all s_b reads done -> safe to overlay s_o

    // ---- banded accs -> LDS [81 ch][68] f32 ----
    float* s_o = (float*)s_b;
    const float inv = 1.0f / 81.0f;
    #define EPI_DY(DD, DYI)                                                   \
        _Pragma("unroll")                                                     \
        for (int reg = 0; reg < 4; ++reg) {                                   \
            const int m = q * 4 + reg;                                        \
            const int t0x = ln - m;             /* dx+4 for nt=0 */           \
            if ((unsigned)t0x <= 8u)                                          \
                s_o[((DYI) * 9 + t0x) * 68 + wvy * 16 + m] = aa0[DD][reg] * inv; \
            const int t1x = ln + 16 - m;        /* dx+4 for nt=1 */           \
            if ((unsigned)t1x <= 8u)                                          \
                s_o[((DYI) * 9 + t1x) * 68 + wvy * 16 + m] = aa1[DD][reg] * inv; \
        }
    if (wvd == 0) {
        #pragma unroll
        for (int dd = 0; dd < 4; ++dd) EPI_DY(dd, dd)
    } else {
        #pragma unroll
        for (int dd = 0; dd < 5; ++dd) EPI_DY(dd, dd + 4)
    }
    __syncthreads();

    // ---- store: 1296 float4 tasks; lanes span x within one (ch,y) row ----
    const size_t ob = (size_t)b * 81 * HW + (size_t)y0 * WID + x0;
    #pragma unroll
    for (int it = 0; it < 3; ++it) {
        const int v = it * THREADS + tid;
        if (v < 1296) {
            const int xq  = v & 3;
            const int row = v >> 2;           // 0..323 = cix*4 + yy
            const int cix = row >> 2;
            const int yy  = row & 3;
            float4v val = *(const float4v*)&s_o[cix * 68 + yy * 16 + xq * 4];
            *(float4v*)&out[ob + s_tab[cix] + yy * WID + xq * 4] = val;
        }
    }
}

// ---------------------------------------------------------------------------
// Fallback (ws too small): R5 fused single kernel (verified passing).
// ---------------------------------------------------------------------------
#define FST_DECODE(TAG, U)                                                    \
    const int u##TAG   = (U);                                                 \
    const int xq##TAG  = u##TAG % 6;                                          \
    const int r6##TAG  = u##TAG / 6;                                          \
    const int oct##TAG = r6##TAG & 15;                                        \
    const int row##TAG = r6##TAG >> 4;                                        \
    const int gr##TAG  = y0 - 4 + row##TAG;                                   \
    const int gx##TAG  = x0 - 4 + xq##TAG * 4;                                \
    const bool ok##TAG = ((unsigned)gr##TAG < (unsigned)HGT) &&               \
                         ((unsigned)gx##TAG < (unsigned)WID);                 \
    const int ga##TAG  = tb + (oct##TAG * 8 * HGT + gr##TAG) * WID + gx##TAG;

#define FST_ISSUE(TAG, COND)                                                  \
    _Pragma("unroll")                                                         \
    for (int j = 0; j < 8; ++j)                                               \
        p##TAG[j] = (COND) ? *(const float4v*)(tgt + ga##TAG + j * HW)        \
                           : (float4v){0.f, 0.f, 0.f, 0.f};

#define FST_WRITE(TAG)                                                        \
    _Pragma("unroll")                                                         \
    for (int i = 0; i < 4; ++i) {                                             \
        const int xl = xq##TAG * 4 + i;                                       \
        uint4 val;                                                            \
        val.x = pk2(p##TAG[0][i], p##TAG[1][i]);                              \
        val.y = pk2(p##TAG[2][i], p##TAG[3][i]);                              \
        val.z = pk2(p##TAG[4][i], p##TAG[5][i]);                              \
        val.w = pk2(p##TAG[6][i], p##TAG[7][i]);                              \
        s_b[(row##TAG * 24 + xl) * 16 + (oct##TAG ^ (xl & 15))] = val;        \
    }

__global__ __launch_bounds__(THREADS, 4)
void cost_volume_fused(const float* __restrict__ src,
                       const float* __restrict__ tgt,
                       float* __restrict__ out) {
    __shared__ __align__(16) uint4 s_b[4736];
    __shared__ int s_tab[81];

    const int tid  = threadIdx.x;
    const int wv   = tid >> 6;
    const int wvy  = wv & 3;
    const int wvd  = wv >> 2;
    const int lane = tid & 63;
    const int q    = lane >> 4;
    const int ln   = lane & 15;

    const int w    = blockIdx.x;
    const int slab = w & 7;
    const int b    = slab >> 1;
    const int yh   = slab & 1;
    const int t    = w >> 3;
    const int x0   = (t % 10) * 16;
    const int y0   = yh * 48 + (t / 10) * 4;

    if (tid < 81) s_tab[tid] = chan_of(tid / 9 - 4, tid % 9 - 4) * HW;

    const int tb = b * CHAN * HGT * WID;

    FST_DECODE(0, tid)
    FST_DECODE(1, tid + 512)
    FST_DECODE(2, tid + 1024)
    const bool has2 = tid < 128;

    float4v p0[8], p1[8], p2[8];
    FST_ISSUE(0, ok0)

    const int y = y0 + wvy;
    const int sbase = (b * CHAN * HGT + y) * WID + x0 + ln + q * 8 * HW;
    float apay[32];
    #pragma unroll
    for (int ks = 0; ks < 4; ++ks)
        #pragma unroll
        for (int j = 0; j < 8; ++j)
            apay[ks * 8 + j] = src[sbase + (ks * 32 + j) * HW];

    FST_ISSUE(1, ok1)
    FST_WRITE(0)
    FST_ISSUE(2, has2 && ok2)
    short8 afr[4];
    #pragma unroll
    for (int ks = 0; ks < 4; ++ks) {
        sl_u f;
        f.v.x = pk2(apay[ks * 8 + 0], apay[ks * 8 + 1]);
        f.v.y = pk2(apay[ks * 8 + 2], apay[ks * 8 + 3]);
        f.v.z = pk2(apay[ks * 8 + 4], apay[ks * 8 + 5]);
        f.v.w = pk2(apay[ks * 8 + 6], apay[ks * 8 + 7]);
        afr[ks] = f.s;
    }
    FST_WRITE(1)
    if (has2) { FST_WRITE(2) }

    __syncthreads();

    float4v aa0[5], aa1[5];
    if (wvd == 0) {
        #pragma unroll
        for (int dd = 0; dd < 4; ++dd) COMPUTE_DY(dd, dd)
    } else {
        #pragma unroll
        for (int dd = 0; dd < 5; ++dd) COMPUTE_DY(dd, dd + 4)
    }

    __syncthreads();

    float* s_o = (float*)s_b;
    const float inv = 1.0f / 81.0f;
    if (wvd == 0) {
        #pragma unroll
        for (int dd = 0; dd < 4; ++dd) EPI_DY(dd, dd)
    } else {
        #pragma unroll
        for (int dd = 0; dd < 5; ++dd) EPI_DY(dd, dd + 4)
    }
    __syncthreads();

    const size_t ob = (size_t)b * 81 * HW + (size_t)y0 * WID + x0;
    #pragma unroll
    for (int it = 0; it < 3; ++it) {
        const int v = it * THREADS + tid;
        if (v < 1296) {
            const int xq  = v & 3;
            const int row = v >> 2;
            const int cix = row >> 2;
            const int yy  = row & 3;
            float4v val = *(const float4v*)&s_o[cix * 68 + yy * 16 + xq * 4];
            *(float4v*)&out[ob + s_tab[cix] + yy * WID + xq * 4] = val;
        }
    }
}

extern "C" void kernel_launch(void* const* d_in, const int* in_sizes, int n_in,
                              void* d_out, int out_size, void* d_ws, size_t ws_size,
                              hipStream_t stream) {
    const float* src = (const float*)d_in[0];
    const float* tgt = (const float*)d_in[1];
    float* out = (float*)d_out;
    if (d_ws && ws_size >= WS_NEED) {
        ushort* ws = (ushort*)d_ws;
        nhwc_bf16_kernel<<<dim3(2304, 1, 1), dim3(256, 1, 1), 0, stream>>>(src, tgt, ws);
        cost_volume_mfma<<<dim3(960, 1, 1), dim3(THREADS, 1, 1), 0, stream>>>(
            ws, ws + TENSOR_ELEMS, out);
    } else {
        cost_volume_fused<<<dim3(960, 1, 1), dim3(THREADS, 1, 1), 0, stream>>>(src, tgt, out);
    }
}

// Round 8
// 117.187 us; speedup vs baseline: 1.0163x; 1.0163x over previous
//
#include <hip/hip_runtime.h>
#include <hip/hip_bf16.h>

#define BATCH 4
#define CHAN 128
#define HGT 96
#define WID 160
#define HW (HGT * WID)
#define THREADS 512
#define TENSOR_ELEMS (BATCH * CHAN * HGT * WID)
#define WS_NEED ((size_t)TENSOR_ELEMS * 2)   // tgt NHWC bf16 only

typedef __attribute__((ext_vector_type(8))) short short8;
typedef __attribute__((ext_vector_type(4))) float float4v;

// Output channel index for displacement (dy,dx), matching _displacements(4) order.
__device__ __forceinline__ int chan_of(int dy, int dx) {
    if (dy == 0 && dx == 0) return 0;
    if (dx == 0) { int i = dy < 0 ? -dy : dy; return 1 + (i - 1) * 20 + (dy < 0 ? 0 : 1); }
    if (dy == 0) { int i = dx < 0 ? -dx : dx; return 1 + (i - 1) * 20 + (dx < 0 ? 2 : 3); }
    int i = dy < 0 ? -dy : dy;
    int j = dx < 0 ? -dx : dx;
    int s = (dy < 0) ? (dx < 0 ? 0 : 2) : (dx < 0 ? 3 : 1);
    return 1 + (i - 1) * 20 + 4 + (j - 1) * 4 + s;
}

// Packed fp32x2 -> bf16x2 (v_cvt_pk_bf16_f32).
__device__ __forceinline__ unsigned pk2(float a, float b) {
    __hip_bfloat162 h = __float22bfloat162_rn(make_float2(a, b));
    unsigned u;
    __builtin_memcpy(&u, &h, 4);
    return u;
}

union sl_u { uint4 v; short8 s; };

// ---------------------------------------------------------------------------
// Pre-pass: tgt NCHW f32 -> NHWC bf16 (R3/R4-verified). src is NOT converted:
// its A-loads are read NCHW f32 in the main kernel (saves 70.8 MB ~ 12 us).
// ---------------------------------------------------------------------------
__global__ __launch_bounds__(256)
void nhwc_bf16_tgt(const float* __restrict__ tgt, ushort* __restrict__ ws) {
    __shared__ unsigned s_t[64][65];
    int r = blockIdx.x;                 // 3 * 96 * 4 = 1152
    const int xb = r % 3; r /= 3;
    const int y  = r % HGT; r /= HGT;
    const int b  = r;                   // 0..3
    const int x0 = xb * 64;
    const int npx = (x0 + 64 <= WID) ? 64 : (WID - x0);   // 64 or 32

    const int t  = threadIdx.x;
    const int x1 = t & 63, cp0 = t >> 6;
    if (x1 < npx) {
        const int base = (b * CHAN * HGT + y) * WID + x0 + x1;  // channel 0
        #pragma unroll
        for (int i = 0; i < 16; ++i) {
            const int cp = cp0 + i * 4;                 // channel pair 0..63
            s_t[cp][x1] = pk2(tgt[base + (2 * cp) * HW],
                              tgt[base + (2 * cp + 1) * HW]);
        }
    }
    __syncthreads();
    const int x2 = t >> 2, g = t & 3;
    if (x2 < npx) {
        ushort* op = ws + ((size_t)(b * HGT + y) * WID + x0 + x2) * CHAN + g * 32;
        #pragma unroll
        for (int k = 0; k < 4; ++k) {
            uint4 v;
            v.x = s_t[g * 16 + k * 4 + 0][x2];
            v.y = s_t[g * 16 + k * 4 + 1][x2];
            v.z = s_t[g * 16 + k * 4 + 2][x2];
            v.w = s_t[g * 16 + k * 4 + 3][x2];
            *(uint4*)(op + k * 8) = v;
        }
    }
}

// ---------------------------------------------------------------------------
// Main kernel: block = (b, y-quad, x-tile), all 81 displacements, 512 threads
// (8 waves; waves 0-3 dy 0-3, waves 4-7 dy 4-8).
//   B: 9 global_load_lds/thread from NHWC bf16 (XOR-octet source swizzle,
//      linear LDS dest, one vmcnt drain at the barrier, 0 bank conflicts).
//   A: NCHW f32, 2-deep chunk pipeline (two named 8-float buffers -> ~32 VGPR
//      live; issued BEFORE the DMA so chunk waits don't gate on DMA ops).
// Epilogue: verified LDS-transpose store path.
// ---------------------------------------------------------------------------
__global__ __launch_bounds__(THREADS, 4)
void cost_volume_mfma(const float* __restrict__ src,
                      const ushort* __restrict__ tgtT,
                      float* __restrict__ out) {
    // 12*24*16 = 4608 DMA slots + 128 pad (nt=1 band-masked reads at x<=31).
    __shared__ __align__(16) uint4 s_b[4736];   // 75776 B -> 2 blocks/CU
    __shared__ int s_tab[81];                   // cix -> oc*HW

    const int tid  = threadIdx.x;
    const int wv   = tid >> 6;        // 0..7
    const int wvy  = wv & 3;          // y sub-row
    const int wvd  = wv >> 2;         // 0: dy 0-3, 1: dy 4-8
    const int lane = tid & 63;
    const int q    = lane >> 4;
    const int ln   = lane & 15;

    // XCD-affinity swizzle: blockIdx%8 -> (batch, y-half) slab.
    const int w    = blockIdx.x;      // 0..959
    const int slab = w & 7;
    const int b    = slab >> 1;
    const int yh   = slab & 1;
    const int t    = w >> 3;          // 0..119
    const int x0   = (t % 10) * 16;
    const int y0   = yh * 48 + (t / 10) * 4;

    // Table build first: its lgkmcnt drain merges into the pre-compute barrier.
    if (tid < 81) s_tab[tid] = chan_of(tid / 9 - 4, tid % 9 - 4) * HW;

    // ---- A (NCHW f32): 2-deep chunked load+cvt pipeline, BEFORE the DMA so
    // per-chunk vmcnt waits never include DMA ops (vmcnt is issue-ordered).
    const int y = y0 + wvy;
    const int sbase = (b * CHAN * HGT + y) * WID + x0 + ln + q * 8 * HW;
    short8 afr[4];
    {
        float c0[8], c1[8];
        #define LOADA(BUF, KS)                                                \
            _Pragma("unroll")                                                 \
            for (int j = 0; j < 8; ++j)                                       \
                BUF[j] = src[sbase + ((KS) * 32 + j) * HW];
        #define CVTA(DST, BUF)                                                \
            {                                                                 \
                sl_u f;                                                       \
                f.v.x = pk2(BUF[0], BUF[1]);                                  \
                f.v.y = pk2(BUF[2], BUF[3]);                                  \
                f.v.z = pk2(BUF[4], BUF[5]);                                  \
                f.v.w = pk2(BUF[6], BUF[7]);                                  \
                DST = f.s;                                                    \
            }
        LOADA(c0, 0)
        LOADA(c1, 1)
        CVTA(afr[0], c0)          // waits chunk0 only (chunk1 in flight)
        LOADA(c0, 2)
        CVTA(afr[1], c1)
        LOADA(c1, 3)
        CVTA(afr[2], c0)
        CVTA(afr[3], c1)
    }

    // ---- stage B: 4608 slots, 9 DMA/thread; slot u=(row*24+x)*16+j holds
    // octet j^(x&15); read for octet o fetches slot o^(x&15).
    const ushort* tbase = tgtT + (size_t)b * HGT * WID * CHAN;
    #pragma unroll
    for (int k = 0; k < 9; ++k) {
        const int u   = k * THREADS + tid;
        const int j   = u & 15;
        const int v16 = u >> 4;              // row*24 + x, 0..287
        const int row = v16 / 24;
        const int x   = v16 - row * 24;
        const int gr  = y0 - 4 + row;        // rows y0-4 .. y0+7
        const int gx  = x0 - 4 + x;
        const int oct = j ^ (x & 15);
        unsigned* lp = (unsigned*)&s_b[k * THREADS + (tid & ~63)];  // wave base
        if (((unsigned)gr < (unsigned)HGT) && ((unsigned)gx < (unsigned)WID)) {
            const unsigned* gp =
                (const unsigned*)(tbase + ((gr * WID + gx) * CHAN + oct * 8));
            __builtin_amdgcn_global_load_lds(gp, lp, 16, 0, 0);
        } else {
            s_b[u] = make_uint4(0u, 0u, 0u, 0u);   // disjoint from DMA targets
        }
    }

    __syncthreads();   // drains DMA (vmcnt) + zero-fill + table (lgkmcnt)

    // ---- compute: this wave's 4 or 5 dys x (8 ds_read_b128 + 8 MFMA) ----
    float4v aa0[5], aa1[5];
    #define COMPUTE_DY(DD, DYI)                                               \
        {                                                                     \
            const int rr = wvy + (DYI);                                       \
            float4v a0 = (float4v){0.f, 0.f, 0.f, 0.f};                       \
            float4v a1 = (float4v){0.f, 0.f, 0.f, 0.f};                       \
            _Pragma("unroll")                                                 \
            for (int ks = 0; ks < 4; ++ks) {                                  \
                sl_u b0;   /* nt=0: x = ln */                                 \
                b0.v = s_b[(rr * 24 + ln) * 16 + ((q + ks * 4) ^ ln)];        \
                a0 = __builtin_amdgcn_mfma_f32_16x16x32_bf16(afr[ks], b0.s, a0, 0, 0, 0); \
            }                                                                 \
            _Pragma("unroll")                                                 \
            for (int ks = 0; ks < 4; ++ks) {                                  \
                sl_u b1;   /* nt=1: x = 16+ln */                              \
                b1.v = s_b[(rr * 24 + 16 + ln) * 16 + ((q + ks * 4) ^ ln)];   \
                a1 = __builtin_amdgcn_mfma_f32_16x16x32_bf16(afr[ks], b1.s, a1, 0, 0, 0); \
            }                                                                 \
            aa0[DD] = a0; aa1[DD] = a1;                                       \
        }
    if (wvd == 0) {
        #pragma unroll
        for (int dd = 0; dd < 4; ++dd) COMPUTE_DY(dd, dd)
    } else {
        #pragma unroll
        for (int dd = 0; dd < 5; ++dd) COMPUTE_DY(dd, dd + 4)
    }

    __syncthreads();   // all s_b reads done -> safe to overlay s_o

    // ---- banded accs -> LDS [81 ch][68] f32 ----
    float* s_o = (float*)s_b;
    const float inv = 1.0f / 81.0f;
    #define EPI_DY(DD, DYI)                                                   \
        _Pragma("unroll")                                                     \
        for (int reg = 0; reg < 4; ++reg) {                                   \
            const int m = q * 4 + reg;                                        \
            const int t0x = ln - m;             /* dx+4 for nt=0 */           \
            if ((unsigned)t0x <= 8u)                                          \
                s_o[((DYI) * 9 + t0x) * 68 + wvy * 16 + m] = aa0[DD][reg] * inv; \
            const int t1x = ln + 16 - m;        /* dx+4 for nt=1 */           \
            if ((unsigned)t1x <= 8u)                                          \
                s_o[((DYI) * 9 + t1x) * 68 + wvy * 16 + m] = aa1[DD][reg] * inv; \
        }
    if (wvd == 0) {
        #pragma unroll
        for (int dd = 0; dd < 4; ++dd) EPI_DY(dd, dd)
    } else {
        #pragma unroll
        for (int dd = 0; dd < 5; ++dd) EPI_DY(dd, dd + 4)
    }
    __syncthreads();

    // ---- store: 1296 float4 tasks; lanes span x within one (ch,y) row ----
    const size_t ob = (size_t)b * 81 * HW + (size_t)y0 * WID + x0;
    #pragma unroll
    for (int it = 0; it < 3; ++it) {
        const int v = it * THREADS + tid;
        if (v < 1296) {
            const int xq  = v & 3;
            const int row = v >> 2;           // 0..323 = cix*4 + yy
            const int cix = row >> 2;
            const int yy  = row & 3;
            float4v val = *(const float4v*)&s_o[cix * 68 + yy * 16 + xq * 4];
            *(float4v*)&out[ob + s_tab[cix] + yy * WID + xq * 4] = val;
        }
    }
}

// ---------------------------------------------------------------------------
// Fallback (ws too small): R5 fused single kernel (verified passing).
// ---------------------------------------------------------------------------
#define FST_DECODE(TAG, U)                                                    \
    const int u##TAG   = (U);                                                 \
    const int xq##TAG  = u##TAG % 6;                                          \
    const int r6##TAG  = u##TAG / 6;                                          \
    const int oct##TAG = r6##TAG & 15;                                        \
    const int row##TAG = r6##TAG >> 4;                                        \
    const int gr##TAG  = y0 - 4 + row##TAG;                                   \
    const int gx##TAG  = x0 - 4 + xq##TAG * 4;                                \
    const bool ok##TAG = ((unsigned)gr##TAG < (unsigned)HGT) &&               \
                         ((unsigned)gx##TAG < (unsigned)WID);                 \
    const int ga##TAG  = tb + (oct##TAG * 8 * HGT + gr##TAG) * WID + gx##TAG;

#define FST_ISSUE(TAG, COND)                                                  \
    _Pragma("unroll")                                                         \
    for (int j = 0; j < 8; ++j)                                               \
        p##TAG[j] = (COND) ? *(const float4v*)(tgt + ga##TAG + j * HW)        \
                           : (float4v){0.f, 0.f, 0.f, 0.f};

#define FST_WRITE(TAG)                                                        \
    _Pragma("unroll")                                                         \
    for (int i = 0; i < 4; ++i) {                                             \
        const int xl = xq##TAG * 4 + i;                                       \
        uint4 val;                                                            \
        val.x = pk2(p##TAG[0][i], p##TAG[1][i]);                              \
        val.y = pk2(p##TAG[2][i], p##TAG[3][i]);                              \
        val.z = pk2(p##TAG[4][i], p##TAG[5][i]);                              \
        val.w = pk2(p##TAG[6][i], p##TAG[7][i]);                              \
        s_b[(row##TAG * 24 + xl) * 16 + (oct##TAG ^ (xl & 15))] = val;        \
    }

__global__ __launch_bounds__(THREADS, 4)
void cost_volume_fused(const float* __restrict__ src,
                       const float* __restrict__ tgt,
                       float* __restrict__ out) {
    __shared__ __align__(16) uint4 s_b[4736];
    __shared__ int s_tab[81];

    const int tid  = threadIdx.x;
    const int wv   = tid >> 6;
    const int wvy  = wv & 3;
    const int wvd  = wv >> 2;
    const int lane = tid & 63;
    const int q    = lane >> 4;
    const int ln   = lane & 15;

    const int w    = blockIdx.x;
    const int slab = w & 7;
    const int b    = slab >> 1;
    const int yh   = slab & 1;
    const int t    = w >> 3;
    const int x0   = (t % 10) * 16;
    const int y0   = yh * 48 + (t / 10) * 4;

    if (tid < 81) s_tab[tid] = chan_of(tid / 9 - 4, tid % 9 - 4) * HW;

    const int tb = b * CHAN * HGT * WID;

    FST_DECODE(0, tid)
    FST_DECODE(1, tid + 512)
    FST_DECODE(2, tid + 1024)
    const bool has2 = tid < 128;

    float4v p0[8], p1[8], p2[8];
    FST_ISSUE(0, ok0)

    const int y = y0 + wvy;
    const int sbase = (b * CHAN * HGT + y) * WID + x0 + ln + q * 8 * HW;
    float apay[32];
    #pragma unroll
    for (int ks = 0; ks < 4; ++ks)
        #pragma unroll
        for (int j = 0; j < 8; ++j)
            apay[ks * 8 + j] = src[sbase + (ks * 32 + j) * HW];

    FST_ISSUE(1, ok1)
    FST_WRITE(0)
    FST_ISSUE(2, has2 && ok2)
    short8 afr[4];
    #pragma unroll
    for (int ks = 0; ks < 4; ++ks) {
        sl_u f;
        f.v.x = pk2(apay[ks * 8 + 0], apay[ks * 8 + 1]);
        f.v.y = pk2(apay[ks * 8 + 2], apay[ks * 8 + 3]);
        f.v.z = pk2(apay[ks * 8 + 4], apay[ks * 8 + 5]);
        f.v.w = pk2(apay[ks * 8 + 6], apay[ks * 8 + 7]);
        afr[ks] = f.s;
    }
    FST_WRITE(1)
    if (has2) { FST_WRITE(2) }

    __syncthreads();

    float4v aa0[5], aa1[5];
    if (wvd == 0) {
        #pragma unroll
        for (int dd = 0; dd < 4; ++dd) COMPUTE_DY(dd, dd)
    } else {
        #pragma unroll
        for (int dd = 0; dd < 5; ++dd) COMPUTE_DY(dd, dd + 4)
    }

    __syncthreads();

    float* s_o = (float*)s_b;
    const float inv = 1.0f / 81.0f;
    if (wvd == 0) {
        #pragma unroll
        for (int dd = 0; dd < 4; ++dd) EPI_DY(dd, dd)
    } else {
        #pragma unroll
        for (int dd = 0; dd < 5; ++dd) EPI_DY(dd, dd + 4)
    }
    __syncthreads();

    const size_t ob = (size_t)b * 81 * HW + (size_t)y0 * WID + x0;
    #pragma unroll
    for (int it = 0; it < 3; ++it) {
        const int v = it * THREADS + tid;
        if (v < 1296) {
            const int xq  = v & 3;
            const int row = v >> 2;
            const int cix = row >> 2;
            const int yy  = row & 3;
            float4v val = *(const float4v*)&s_o[cix * 68 + yy * 16 + xq * 4];
            *(float4v*)&out[ob + s_tab[cix] + yy * WID + xq * 4] = val;
        }
    }
}

extern "C" void kernel_launch(void* const* d_in, const int* in_sizes, int n_in,
                              void* d_out, int out_size, void* d_ws, size_t ws_size,
                              hipStream_t stream) {
    const float* src = (const float*)d_in[0];
    const float* tgt = (const float*)d_in[1];
    float* out = (float*)d_out;
    if (d_ws && ws_size >= WS_NEED) {
        ushort* ws = (ushort*)d_ws;
        nhwc_bf16_tgt<<<dim3(1152, 1, 1), dim3(256, 1, 1), 0, stream>>>(tgt, ws);
        cost_volume_mfma<<<dim3(960, 1, 1), dim3(THREADS, 1, 1), 0, stream>>>(src, ws, out);
    } else {
        cost_volume_fused<<<dim3(960, 1, 1), dim3(THREADS, 1, 1), 0, stream>>>(src, tgt, out);
    }
}